// Round 10
// baseline (743.100 us; speedup 1.0000x reference)
//
#include <hip/hip_runtime.h>
#include <hip/hip_fp16.h>
#include <hip/hip_cooperative_groups.h>
#include <cstddef>

namespace cg = cooperative_groups;

#define N_NODES 50000
#define E_EDGES 1600000
#define NEG_SLOPE 0.2f
#define LN_EPS 1e-5f
#define LOG2E 1.4426950408889634f
#define PAD 96        // max in-degree; Poisson(32) -> P(deg>96) ~ 1e-19

#define NBK 196       // dst buckets of 256 nodes
#define BCAP 10240    // entries per bucket (mean 8192, >20 sigma headroom)
#define PCH 4096      // edges per partition chunk
#define NCH 391       // ceil(E/PCH)
#define TPB 256

// ---------------- workspace layout (bytes) ----------------
// scal[0] = ew_sum, scal[4..7] = K[h]
#define OFF_SCAL    0u
#define OFF_BCUR    256u                       // NBK ints
#define OFF_EWPART  2048u                      // NCH floats
#define OFF_COUNTS  4096u                      // N ints -> 204,096
#define OFF_ASRC    204160u                    // N*4 floats -> 1,004,160
#define OFF_ADST    1004160u                   // N*4 floats -> 1,804,160
#define OFF_XPH     1804160u                   // N*128 halfs -> 14,604,160
#define OFF_PAIRS   14604160u                  // N*PAD uints -> 33,804,160
#define OFF_STAGE   33804160u                  // NBK*BCAP uint2 -> 49,860,480

__device__ __forceinline__ float lrelu(float x) { return x > 0.f ? x : NEG_SLOPE * x; }

__device__ __forceinline__ float4 fma4(float s, float4 a, float4 c) {
    c.x = fmaf(s, a.x, c.x); c.y = fmaf(s, a.y, c.y);
    c.z = fmaf(s, a.z, c.z); c.w = fmaf(s, a.w, c.w);
    return c;
}

// xp = x @ W (stored fp16); a_src[n,h], a_dst[n,h].
__global__ __launch_bounds__(256) void k_gemm(const float* __restrict__ x, const float* __restrict__ W,
                                              const float* __restrict__ att_src, const float* __restrict__ att_dst,
                                              unsigned short* __restrict__ xph, float* __restrict__ a_src,
                                              float* __restrict__ a_dst) {
    __shared__ float sx[64 * 128];  // 32 KB
    __shared__ float sW[64 * 128];  // 32 KB
    int t = threadIdx.x;
    int r0 = blockIdx.x * 64;
    int tc = t & 31;   // cols tc*4 .. tc*4+3
    int tr = t >> 5;   // rows tr*8 .. tr*8+7

    for (int i = t; i < 2048; i += 256) {
        int row = i >> 5;
        float4 v = make_float4(0.f, 0.f, 0.f, 0.f);
        if (r0 + row < N_NODES) v = ((const float4*)x)[(size_t)(r0 + row) * 32 + (i & 31)];
        ((float4*)sx)[i] = v;
    }

    float4 acc[8];
    #pragma unroll
    for (int r = 0; r < 8; r++) acc[r] = make_float4(0.f, 0.f, 0.f, 0.f);

    for (int kc = 0; kc < 128; kc += 64) {
        __syncthreads();
        for (int i = t; i < 2048; i += 256)
            ((float4*)sW)[i] = ((const float4*)W)[(size_t)kc * 32 + i];
        __syncthreads();
        #pragma unroll 4
        for (int k4 = 0; k4 < 16; k4++) {
            float4 w0 = ((float4*)sW)[(k4 * 4 + 0) * 32 + tc];
            float4 w1 = ((float4*)sW)[(k4 * 4 + 1) * 32 + tc];
            float4 w2 = ((float4*)sW)[(k4 * 4 + 2) * 32 + tc];
            float4 w3 = ((float4*)sW)[(k4 * 4 + 3) * 32 + tc];
            #pragma unroll
            for (int r = 0; r < 8; r++) {
                float4 xv = ((float4*)sx)[(tr * 8 + r) * 32 + (kc >> 2) + k4];
                acc[r] = fma4(xv.x, w0, acc[r]);
                acc[r] = fma4(xv.y, w1, acc[r]);
                acc[r] = fma4(xv.z, w2, acc[r]);
                acc[r] = fma4(xv.w, w3, acc[r]);
            }
        }
    }

    float4 s4 = ((const float4*)att_src)[tc];
    float4 d4 = ((const float4*)att_dst)[tc];
    int h = tc >> 3;
    #pragma unroll
    for (int r = 0; r < 8; r++) {
        int row = r0 + tr * 8 + r;
        if (row < N_NODES) {
            __half2 h01 = __floats2half2_rn(acc[r].x, acc[r].y);
            __half2 h23 = __floats2half2_rn(acc[r].z, acc[r].w);
            uint2 pk;
            pk.x = *(unsigned int*)&h01;
            pk.y = *(unsigned int*)&h23;
            ((uint2*)xph)[(size_t)row * 32 + tc] = pk;
            float ps = acc[r].x * s4.x + acc[r].y * s4.y + acc[r].z * s4.z + acc[r].w * s4.w;
            float pd = acc[r].x * d4.x + acc[r].y * d4.y + acc[r].z * d4.z + acc[r].w * d4.w;
            ps += __shfl_down(ps, 4, 8); ps += __shfl_down(ps, 2, 8); ps += __shfl_down(ps, 1, 8);
            pd += __shfl_down(pd, 4, 8); pd += __shfl_down(pd, 2, 8); pd += __shfl_down(pd, 1, 8);
            if ((tc & 7) == 0) {
                a_src[(size_t)row * 4 + h] = ps;
                a_dst[(size_t)row * 4 + h] = pd;
            }
        }
    }
}

// one cooperative kernel: init -> partition -> bucket(+ew total) -> aggregate.
// ALL phases are grid-stride, so any co-resident grid size is correct.
__global__ __launch_bounds__(TPB, 6) void k_fused(
    const int* __restrict__ ei, const float* __restrict__ ew,
    const float* __restrict__ W_edge, const float* __restrict__ att_edge,
    const unsigned short* __restrict__ xph, const float* __restrict__ a_src,
    const float* __restrict__ a_dst, const float* __restrict__ bias,
    const float* __restrict__ gamma, const float* __restrict__ beta,
    float* __restrict__ scal, int* __restrict__ bcur, float* __restrict__ ewPart,
    int* __restrict__ counts, unsigned int* __restrict__ pairs,
    uint2* __restrict__ staging, float* __restrict__ out)
{
    cg::grid_group grid = cg::this_grid();
    int t = threadIdx.x;
    int b = blockIdx.x;
    int gn = gridDim.x;

    // phase-1 shared
    __shared__ int cntP[NBK];
    __shared__ int gbase[NBK];
    __shared__ unsigned short lrS[PCH];
    __shared__ float wred[4];
    // phase-2 shared
    __shared__ int cnt2[256];
    // phase-3 shared
    __shared__ float sAlpha[TPB * 4];
    __shared__ int   sSrc[TPB];
    __shared__ float sSelf[4];
    __shared__ float4 sDenW[4];
    __shared__ float4 sXw[128];

    // ---------- phase 0: init ----------
    if (b == 0) {
        for (int i = t; i < NBK; i += TPB) bcur[i] = 0;
        if (t < 128) {
            float p = W_edge[t] * att_edge[t];
            #pragma unroll
            for (int off = 16; off; off >>= 1) p += __shfl_down(p, off, 32);
            if ((t & 31) == 0) scal[4 + (t >> 5)] = p;
        }
    }
    grid.sync();

    // ---------- phase 1: partition into 256-node dst buckets ----------
    for (int ch = b; ch < NCH; ch += gn) {
        for (int i = t; i < NBK; i += TPB) cntP[i] = 0;
        __syncthreads();
        int e0 = ch * PCH;
        int emax = min(PCH, E_EDGES - e0);
        float s_ew = 0.f;
        #pragma unroll
        for (int i = 0; i < 16; i++) {
            int idx = i * TPB + t;
            if (idx < emax) {
                int e = e0 + idx;
                int d = ei[E_EDGES + e];
                s_ew += ew[e];
                lrS[idx] = (unsigned short)atomicAdd(&cntP[d >> 8], 1);
            }
        }
        #pragma unroll
        for (int off = 32; off; off >>= 1) s_ew += __shfl_down(s_ew, off, 64);
        if ((t & 63) == 0) wred[t >> 6] = s_ew;
        __syncthreads();           // cntP + wred complete
        if (t == 0) ewPart[ch] = wred[0] + wred[1] + wred[2] + wred[3];
        for (int i = t; i < NBK; i += TPB) gbase[i] = atomicAdd(&bcur[i], cntP[i]);
        __syncthreads();
        #pragma unroll
        for (int i = 0; i < 16; i++) {
            int idx = i * TPB + t;
            if (idx < emax) {
                int e = e0 + idx;
                int s = ei[e];
                int d = ei[E_EDGES + e];
                float w = ew[e];
                int bk = d >> 8;
                uint2 ent;
                ent.x = (unsigned int)s |
                        ((unsigned int)__half_as_ushort(__float2half_rn(w)) << 16);
                ent.y = (unsigned int)d;
                staging[(size_t)bk * BCAP + gbase[bk] + (int)lrS[idx]] = ent;
            }
        }
        __syncthreads();           // done with cntP/gbase/lrS before next chunk
    }
    grid.sync();

    // ---------- phase 2: bucket -> padded CSR + counts; ew total ----------
    if (b == 0) {
        float s = 0.f;
        for (int i = t; i < NCH; i += TPB) s += ewPart[i];
        #pragma unroll
        for (int off = 32; off; off >>= 1) s += __shfl_down(s, off, 64);
        if ((t & 63) == 0) wred[t >> 6] = s;
        __syncthreads();
        if (t == 0) scal[0] = wred[0] + wred[1] + wred[2] + wred[3];
    }
    for (int bk = b; bk < NBK; bk += gn) {
        cnt2[t] = 0;
        __syncthreads();
        int tot = bcur[bk];
        const uint2* sg = staging + (size_t)bk * BCAP;
        for (int i = t; i < tot; i += TPB) {
            uint2 ent = sg[i];
            int d = (int)ent.y;
            int r = atomicAdd(&cnt2[d & 255], 1);
            pairs[(size_t)d * PAD + r] = ent.x;
        }
        __syncthreads();
        int n = (bk << 8) + t;
        if (n < N_NODES) counts[n] = cnt2[t];
        __syncthreads();           // cnt2 reuse
    }
    grid.sync();

    // ---------- phase 3: softmax-weighted gather + bias + LN + ELU ----------
    const float4 K = *(const float4*)(scal + 4);
    const float mean_ew = scal[0] * (1.0f / E_EDGES);
    int g = t >> 5, c = t & 31, h = c >> 3;
    int lane = t & 63, wv = t >> 6;

    for (int n = b; n < N_NODES; n += gn) {
        int cnt = counts[n];
        size_t base = (size_t)n * PAD;
        float4 ad = *(const float4*)(a_dst + (size_t)4 * n);

        if (t < 4) {
            float as_h = a_src[(size_t)4 * n + t];
            float ad_h = a_dst[(size_t)4 * n + t];
            float K_h  = scal[4 + t];
            sSelf[t] = exp2f(lrelu(as_h + ad_h + K_h * mean_ew) * LOG2E);
        }
        __syncthreads();

        float4 acc = make_float4(0.f, 0.f, 0.f, 0.f);
        float4 den = make_float4(0.f, 0.f, 0.f, 0.f);

        for (int be = 0; be < cnt; be += TPB) {
            int e = be + t;
            float a0 = 0.f, a1 = 0.f, a2 = 0.f, a3 = 0.f;
            int s = n;
            if (e < cnt) {
                unsigned int pk = pairs[base + e];
                s = (int)(pk & 0xFFFFu);
                float w = __half2float(__ushort_as_half((unsigned short)(pk >> 16)));
                float4 av = *(const float4*)(a_src + (size_t)4 * s);
                a0 = exp2f(lrelu(av.x + ad.x + K.x * w) * LOG2E);
                a1 = exp2f(lrelu(av.y + ad.y + K.y * w) * LOG2E);
                a2 = exp2f(lrelu(av.z + ad.z + K.z * w) * LOG2E);
                a3 = exp2f(lrelu(av.w + ad.w + K.w * w) * LOG2E);
            }
            sSrc[t] = s;
            ((float4*)sAlpha)[t] = make_float4(a0, a1, a2, a3);
            den.x += a0; den.y += a1; den.z += a2; den.w += a3;
            __syncthreads();

            int nn = min(TPB, cnt - be);
            int steps = (nn + 7) >> 3;
            for (int i = 0; i < steps; i++) {
                int ee = i * 8 + g;
                float a = sAlpha[ee * 4 + h];
                int s2 = sSrc[ee];
                uint2 pv = ((const uint2*)xph)[(size_t)s2 * 32 + c];
                __half2 h01 = *(__half2*)&pv.x;
                __half2 h23 = *(__half2*)&pv.y;
                float2 f01 = __half22float2(h01);
                float2 f23 = __half22float2(h23);
                acc.x = fmaf(a, f01.x, acc.x);
                acc.y = fmaf(a, f01.y, acc.y);
                acc.z = fmaf(a, f23.x, acc.z);
                acc.w = fmaf(a, f23.y, acc.w);
            }
            __syncthreads();
        }

        // per-head denominators: wave reduce, stash per wave
        #pragma unroll
        for (int off = 32; off; off >>= 1) {
            den.x += __shfl_down(den.x, off, 64);
            den.y += __shfl_down(den.y, off, 64);
            den.z += __shfl_down(den.z, off, 64);
            den.w += __shfl_down(den.w, off, 64);
        }
        if (lane == 0) sDenW[wv] = den;

        // merge the 2 groups within each wave, stash per-wave partials
        acc.x += __shfl_xor(acc.x, 32, 64);
        acc.y += __shfl_xor(acc.y, 32, 64);
        acc.z += __shfl_xor(acc.z, 32, 64);
        acc.w += __shfl_xor(acc.w, 32, 64);
        if (lane < 32) sXw[wv * 32 + lane] = acc;
        __syncthreads();

        if (t < 32) {
            float4 p0 = sXw[t], p1 = sXw[32 + t], p2 = sXw[64 + t], p3 = sXw[96 + t];
            acc.x = p0.x + p1.x + p2.x + p3.x;
            acc.y = p0.y + p1.y + p2.y + p3.y;
            acc.z = p0.z + p1.z + p2.z + p3.z;
            acc.w = p0.w + p1.w + p2.w + p3.w;

            int hh = t >> 3;
            float aself = sSelf[hh];
            uint2 pv = ((const uint2*)xph)[(size_t)n * 32 + t];
            __half2 h01 = *(__half2*)&pv.x;
            __half2 h23 = *(__half2*)&pv.y;
            float2 f01 = __half22float2(h01);
            float2 f23 = __half22float2(h23);
            acc.x = fmaf(aself, f01.x, acc.x);
            acc.y = fmaf(aself, f01.y, acc.y);
            acc.z = fmaf(aself, f23.x, acc.z);
            acc.w = fmaf(aself, f23.y, acc.w);

            const float* dptr = (const float*)sDenW;
            float dsum = dptr[hh] + dptr[4 + hh] + dptr[8 + hh] + dptr[12 + hh] + aself;
            float inv = 1.0f / (dsum + 1e-16f);
            float4 b4 = ((const float4*)bias)[t];
            float4 y;
            y.x = acc.x * inv + b4.x; y.y = acc.y * inv + b4.y;
            y.z = acc.z * inv + b4.z; y.w = acc.w * inv + b4.w;

            float s1 = y.x + y.y + y.z + y.w;
            #pragma unroll
            for (int off = 16; off; off >>= 1) s1 += __shfl_down(s1, off, 32);
            float mu = __shfl(s1, 0, 32) * (1.f / 128.f);
            float4 dv;
            dv.x = y.x - mu; dv.y = y.y - mu; dv.z = y.z - mu; dv.w = y.w - mu;
            float s2 = dv.x * dv.x + dv.y * dv.y + dv.z * dv.z + dv.w * dv.w;
            #pragma unroll
            for (int off = 16; off; off >>= 1) s2 += __shfl_down(s2, off, 32);
            float var = __shfl(s2, 0, 32) * (1.f / 128.f);
            float rstd = rsqrtf(var + LN_EPS);
            float4 g4 = ((const float4*)gamma)[t];
            float4 be4 = ((const float4*)beta)[t];
            float4 o;
            o.x = dv.x * rstd * g4.x + be4.x;
            o.y = dv.y * rstd * g4.y + be4.y;
            o.z = dv.z * rstd * g4.z + be4.z;
            o.w = dv.w * rstd * g4.w + be4.w;
            o.x = o.x > 0.f ? o.x : expm1f(o.x);
            o.y = o.y > 0.f ? o.y : expm1f(o.y);
            o.z = o.z > 0.f ? o.z : expm1f(o.z);
            o.w = o.w > 0.f ? o.w : expm1f(o.w);
            ((float4*)out)[(size_t)n * 32 + t] = o;
        }
        __syncthreads();           // sSelf/sXw/sDenW reuse next node
    }
}

extern "C" void kernel_launch(void* const* d_in, const int* in_sizes, int n_in,
                              void* d_out, int out_size, void* d_ws, size_t ws_size,
                              hipStream_t stream) {
    const float* x        = (const float*)d_in[0];
    const int*   ei       = (const int*)d_in[1];
    const float* ew       = (const float*)d_in[2];
    const float* W        = (const float*)d_in[3];
    const float* att_src  = (const float*)d_in[4];
    const float* att_dst  = (const float*)d_in[5];
    const float* W_edge   = (const float*)d_in[6];
    const float* att_edge = (const float*)d_in[7];
    const float* bias     = (const float*)d_in[8];
    const float* gamma    = (const float*)d_in[9];
    const float* beta     = (const float*)d_in[10];
    float* out = (float*)d_out;

    char* ws = (char*)d_ws;
    float* scal      = (float*)(ws + OFF_SCAL);
    int*   bcur      = (int*)(ws + OFF_BCUR);
    float* ewPart    = (float*)(ws + OFF_EWPART);
    int*   counts    = (int*)(ws + OFF_COUNTS);
    float* a_src     = (float*)(ws + OFF_ASRC);
    float* a_dst     = (float*)(ws + OFF_ADST);
    unsigned short* xph = (unsigned short*)(ws + OFF_XPH);
    unsigned int* pairs = (unsigned int*)(ws + OFF_PAIRS);
    uint2* staging   = (uint2*)(ws + OFF_STAGE);

    k_gemm<<<(N_NODES + 63) / 64, 256, 0, stream>>>(x, W, att_src, att_dst, xph, a_src, a_dst);

    // size the cooperative grid from actual achievable occupancy (deterministic,
    // host-side query only — safe under graph capture)
    int occ = 0;
    hipError_t oe = hipOccupancyMaxActiveBlocksPerMultiprocessor(&occ, (const void*)k_fused, TPB, 0);
    if (oe != hipSuccess || occ < 1) occ = 1;
    int grid = occ * 256;
    if (grid > 2048) grid = 2048;

    void* kargs[] = {
        (void*)&ei, (void*)&ew, (void*)&W_edge, (void*)&att_edge,
        (void*)&xph, (void*)&a_src, (void*)&a_dst, (void*)&bias,
        (void*)&gamma, (void*)&beta, (void*)&scal, (void*)&bcur,
        (void*)&ewPart, (void*)&counts, (void*)&pairs, (void*)&staging,
        (void*)&out
    };
    hipLaunchCooperativeKernel((void*)k_fused, dim3(grid), dim3(TPB), kargs, 0, stream);
}

// Round 11
// 632.064 us; speedup vs baseline: 1.1757x; 1.1757x over previous
//
#include <hip/hip_runtime.h>
#include <hip/hip_fp16.h>
#include <hip/hip_cooperative_groups.h>
#include <cstddef>

namespace cg = cooperative_groups;

#define N_NODES 50000
#define E_EDGES 1600000
#define NEG_SLOPE 0.2f
#define LN_EPS 1e-5f
#define LOG2E 1.4426950408889634f
#define PAD 96        // max in-degree; Poisson(32) -> P(deg>96) ~ 1e-19

#define NBK 196       // dst buckets of 256 nodes
#define BCAP 10240    // entries per bucket (mean 8192, >20 sigma headroom)
#define PCH 2048      // edges per partition chunk
#define NCH 782       // ceil(E/PCH)
#define TPB 256

// ---------------- workspace layout (bytes) ----------------
// scal[0] = ew_sum, scal[4..7] = K[h]
#define OFF_SCAL    0u
#define OFF_BCUR    256u                       // NBK ints -> 1040
#define OFF_EWPART  2048u                      // NCH floats -> 5176
#define OFF_COUNTS  8192u                      // N ints -> 208,192
#define OFF_ASRC    208256u                    // N*4 floats -> 1,008,256
#define OFF_ADST    1008256u                   // N*4 floats -> 1,808,256
#define OFF_XPH     1808256u                   // N*128 halfs -> 14,608,256
#define OFF_PAIRS   14608256u                  // N*PAD uints -> 33,808,256
#define OFF_STAGE   33808256u                  // NBK*BCAP uint2 -> 49,864,576

__device__ __forceinline__ float lrelu(float x) { return x > 0.f ? x : NEG_SLOPE * x; }

__device__ __forceinline__ float sel4(float4 v, int h) {
    float ab = (h & 1) ? v.y : v.x;
    float cd = (h & 1) ? v.w : v.z;
    return (h & 2) ? cd : ab;
}

__device__ __forceinline__ float4 fma4(float s, float4 a, float4 c) {
    c.x = fmaf(s, a.x, c.x); c.y = fmaf(s, a.y, c.y);
    c.z = fmaf(s, a.z, c.z); c.w = fmaf(s, a.w, c.w);
    return c;
}

// ---------------- phase 1: partition edges into 256-node dst buckets ----------
__device__ void phase1(const int* __restrict__ ei, const float* __restrict__ ew,
                       int* __restrict__ bcur, float* __restrict__ ewPart,
                       uint2* __restrict__ staging, int b, int gn)
{
    __shared__ int cntP[NBK];
    __shared__ int gbase[NBK];
    __shared__ unsigned short lrS[PCH];
    __shared__ float wred[4];
    int t = threadIdx.x;
    for (int ch = b; ch < NCH; ch += gn) {
        for (int i = t; i < NBK; i += TPB) cntP[i] = 0;
        __syncthreads();
        int e0 = ch * PCH;
        int emax = min(PCH, E_EDGES - e0);
        float s_ew = 0.f;
        #pragma unroll
        for (int i = 0; i < 8; i++) {
            int idx = i * TPB + t;
            if (idx < emax) {
                int e = e0 + idx;
                int d = ei[E_EDGES + e];
                s_ew += ew[e];
                lrS[idx] = (unsigned short)atomicAdd(&cntP[d >> 8], 1);
            }
        }
        #pragma unroll
        for (int off = 32; off; off >>= 1) s_ew += __shfl_down(s_ew, off, 64);
        if ((t & 63) == 0) wred[t >> 6] = s_ew;
        __syncthreads();           // cntP + wred complete
        if (t == 0) ewPart[ch] = wred[0] + wred[1] + wred[2] + wred[3];
        for (int i = t; i < NBK; i += TPB) gbase[i] = atomicAdd(&bcur[i], cntP[i]);
        __syncthreads();
        #pragma unroll
        for (int i = 0; i < 8; i++) {
            int idx = i * TPB + t;
            if (idx < emax) {
                int e = e0 + idx;
                int s = ei[e];
                int d = ei[E_EDGES + e];
                float w = ew[e];
                int bk = d >> 8;
                uint2 ent;
                ent.x = (unsigned int)s |
                        ((unsigned int)__half_as_ushort(__float2half_rn(w)) << 16);
                ent.y = (unsigned int)d;
                staging[(size_t)bk * BCAP + gbase[bk] + (int)lrS[idx]] = ent;
            }
        }
        __syncthreads();           // cntP/gbase/lrS reuse next chunk
    }
}

// ---------------- phase 2: bucket -> padded CSR + counts; ew total -----------
__device__ void phase2(const uint2* __restrict__ staging, const int* __restrict__ bcur,
                       const float* __restrict__ ewPart, unsigned int* __restrict__ pairs,
                       int* __restrict__ counts, float* __restrict__ scal, int b, int gn)
{
    __shared__ int cnt2[256];
    __shared__ float wr2[4];
    int t = threadIdx.x;
    if (b == 0) {
        float s = 0.f;
        for (int i = t; i < NCH; i += TPB) s += ewPart[i];
        #pragma unroll
        for (int off = 32; off; off >>= 1) s += __shfl_down(s, off, 64);
        if ((t & 63) == 0) wr2[t >> 6] = s;
        __syncthreads();
        if (t == 0) scal[0] = wr2[0] + wr2[1] + wr2[2] + wr2[3];
    }
    for (int bk = b; bk < NBK; bk += gn) {
        cnt2[t] = 0;
        __syncthreads();
        int tot = bcur[bk];
        const uint2* sg = staging + (size_t)bk * BCAP;
        for (int i = t; i < tot; i += TPB) {
            uint2 ent = sg[i];
            int d = (int)ent.y;
            int r = atomicAdd(&cnt2[d & 255], 1);
            pairs[(size_t)d * PAD + r] = ent.x;
        }
        __syncthreads();
        int n = (bk << 8) + t;
        if (n < N_NODES) counts[n] = cnt2[t];
        __syncthreads();           // cnt2 reuse
    }
}

// ---------------- phase 3: wave-per-node aggregate (NO barriers) -------------
__device__ void phase3(const unsigned int* __restrict__ xpu, const float* __restrict__ a_src,
                       const float* __restrict__ a_dst, const int* __restrict__ counts,
                       const unsigned int* __restrict__ pairs, const float* __restrict__ scal,
                       const float* __restrict__ bias, const float* __restrict__ gamma,
                       const float* __restrict__ beta, float* __restrict__ out,
                       int wid, int wstride)
{
    int lane = threadIdx.x & 63;
    int h = lane >> 4;        // head for this lane's channel pair
    int em = lane & 15;       // edge slot within a 16-edge batch
    int shb = lane & 48;      // shuffle base: lane h*16 holds this head's alphas
    float4 K = *(const float4*)(scal + 4);
    float Kh = sel4(K, h);
    float mean_ew = scal[0] * (1.0f / E_EDGES);

    for (int n = wid; n < N_NODES; n += wstride) {
        int cnt = counts[n];
        float4 ad4 = *(const float4*)(a_dst + (size_t)4 * n);
        float4 as4 = *(const float4*)(a_src + (size_t)4 * n);
        float adh = sel4(ad4, h);
        float aself = exp2f(lrelu(sel4(as4, h) + adh + Kh * mean_ew) * LOG2E);

        unsigned int pv = xpu[(size_t)n * 64 + lane];   // channels 2l, 2l+1
        float2 f = __half22float2(*(__half2*)&pv);
        float acc0 = aself * f.x, acc1 = aself * f.y;
        float den = 0.f;

        for (int base = 0; base < cnt; base += 16) {
            int e = base + em;
            float alpha = 0.f;
            int s = 0;
            if (e < cnt) {
                unsigned int pk = pairs[(size_t)n * PAD + e];
                s = (int)(pk & 0xFFFFu);
                float w = __half2float(__ushort_as_half((unsigned short)(pk >> 16)));
                float4 av = *(const float4*)(a_src + (size_t)4 * s);
                alpha = exp2f(lrelu(sel4(av, h) + adh + Kh * w) * LOG2E);
            }
            den += alpha;          // lane's own head, em-strided edges
            int nn = min(16, cnt - base);
            for (int j = 0; j < nn; j++) {
                int sj   = __shfl(s, shb + j, 64);
                float aj = __shfl(alpha, shb + j, 64);
                unsigned int p2 = xpu[(size_t)sj * 64 + lane];
                float2 g = __half22float2(*(__half2*)&p2);
                acc0 = fmaf(aj, g.x, acc0);
                acc1 = fmaf(aj, g.y, acc1);
            }
        }
        // reduce den across the 16 lanes sharing this head
        den += __shfl_xor(den, 1, 64);
        den += __shfl_xor(den, 2, 64);
        den += __shfl_xor(den, 4, 64);
        den += __shfl_xor(den, 8, 64);
        den += aself;

        float inv = 1.0f / (den + 1e-16f);
        float2 b2 = ((const float2*)bias)[lane];
        float y0 = fmaf(acc0, inv, b2.x);
        float y1 = fmaf(acc1, inv, b2.y);

        // LayerNorm over 128 channels (2 per lane) via full-wave xor reduce
        float s1 = y0 + y1;
        #pragma unroll
        for (int off = 1; off < 64; off <<= 1) s1 += __shfl_xor(s1, off, 64);
        float mu = s1 * (1.f / 128.f);
        float d0 = y0 - mu, d1 = y1 - mu;
        float s2 = d0 * d0 + d1 * d1;
        #pragma unroll
        for (int off = 1; off < 64; off <<= 1) s2 += __shfl_xor(s2, off, 64);
        float rstd = rsqrtf(s2 * (1.f / 128.f) + LN_EPS);
        float2 g2 = ((const float2*)gamma)[lane];
        float2 be2 = ((const float2*)beta)[lane];
        float o0 = fmaf(d0 * rstd, g2.x, be2.x);
        float o1 = fmaf(d1 * rstd, g2.y, be2.y);
        o0 = o0 > 0.f ? o0 : expm1f(o0);
        o1 = o1 > 0.f ? o1 : expm1f(o1);
        float2 o; o.x = o0; o.y = o1;
        ((float2*)out)[(size_t)n * 64 + lane] = o;
    }
}

// xp = x @ W (stored fp16); a_src[n,h], a_dst[n,h]; block 0 also zeroes bcur
// and computes K[h] (so k_fused needs no init phase).
__global__ __launch_bounds__(256) void k_gemm(const float* __restrict__ x, const float* __restrict__ W,
                                              const float* __restrict__ att_src, const float* __restrict__ att_dst,
                                              const float* __restrict__ W_edge, const float* __restrict__ att_edge,
                                              unsigned short* __restrict__ xph, float* __restrict__ a_src,
                                              float* __restrict__ a_dst, float* __restrict__ scal,
                                              int* __restrict__ bcur) {
    __shared__ float sx[64 * 128];  // 32 KB
    __shared__ float sW[64 * 128];  // 32 KB
    int t = threadIdx.x;
    if (blockIdx.x == 0) {
        if (t < NBK) bcur[t] = 0;
        if (t < 128) {
            float p = W_edge[t] * att_edge[t];
            #pragma unroll
            for (int off = 16; off; off >>= 1) p += __shfl_down(p, off, 32);
            if ((t & 31) == 0) scal[4 + (t >> 5)] = p;
        }
    }
    int r0 = blockIdx.x * 64;
    int tc = t & 31;
    int tr = t >> 5;

    for (int i = t; i < 2048; i += 256) {
        int row = i >> 5;
        float4 v = make_float4(0.f, 0.f, 0.f, 0.f);
        if (r0 + row < N_NODES) v = ((const float4*)x)[(size_t)(r0 + row) * 32 + (i & 31)];
        ((float4*)sx)[i] = v;
    }

    float4 acc[8];
    #pragma unroll
    for (int r = 0; r < 8; r++) acc[r] = make_float4(0.f, 0.f, 0.f, 0.f);

    for (int kc = 0; kc < 128; kc += 64) {
        __syncthreads();
        for (int i = t; i < 2048; i += 256)
            ((float4*)sW)[i] = ((const float4*)W)[(size_t)kc * 32 + i];
        __syncthreads();
        #pragma unroll 4
        for (int k4 = 0; k4 < 16; k4++) {
            float4 w0 = ((float4*)sW)[(k4 * 4 + 0) * 32 + tc];
            float4 w1 = ((float4*)sW)[(k4 * 4 + 1) * 32 + tc];
            float4 w2 = ((float4*)sW)[(k4 * 4 + 2) * 32 + tc];
            float4 w3 = ((float4*)sW)[(k4 * 4 + 3) * 32 + tc];
            #pragma unroll
            for (int r = 0; r < 8; r++) {
                float4 xv = ((float4*)sx)[(tr * 8 + r) * 32 + (kc >> 2) + k4];
                acc[r] = fma4(xv.x, w0, acc[r]);
                acc[r] = fma4(xv.y, w1, acc[r]);
                acc[r] = fma4(xv.z, w2, acc[r]);
                acc[r] = fma4(xv.w, w3, acc[r]);
            }
        }
    }

    float4 s4 = ((const float4*)att_src)[tc];
    float4 d4 = ((const float4*)att_dst)[tc];
    int h = tc >> 3;
    #pragma unroll
    for (int r = 0; r < 8; r++) {
        int row = r0 + tr * 8 + r;
        if (row < N_NODES) {
            __half2 h01 = __floats2half2_rn(acc[r].x, acc[r].y);
            __half2 h23 = __floats2half2_rn(acc[r].z, acc[r].w);
            uint2 pk;
            pk.x = *(unsigned int*)&h01;
            pk.y = *(unsigned int*)&h23;
            ((uint2*)xph)[(size_t)row * 32 + tc] = pk;
            float ps = acc[r].x * s4.x + acc[r].y * s4.y + acc[r].z * s4.z + acc[r].w * s4.w;
            float pd = acc[r].x * d4.x + acc[r].y * d4.y + acc[r].z * d4.z + acc[r].w * d4.w;
            ps += __shfl_down(ps, 4, 8); ps += __shfl_down(ps, 2, 8); ps += __shfl_down(ps, 1, 8);
            pd += __shfl_down(pd, 4, 8); pd += __shfl_down(pd, 2, 8); pd += __shfl_down(pd, 1, 8);
            if ((tc & 7) == 0) {
                a_src[(size_t)row * 4 + h] = ps;
                a_dst[(size_t)row * 4 + h] = pd;
            }
        }
    }
}

// cooperative: partition -> bucket -> wave-per-node aggregate
__global__ __launch_bounds__(TPB) void k_fused(
    const int* __restrict__ ei, const float* __restrict__ ew,
    const unsigned short* __restrict__ xph, const float* __restrict__ a_src,
    const float* __restrict__ a_dst, const float* __restrict__ bias,
    const float* __restrict__ gamma, const float* __restrict__ beta,
    float* __restrict__ scal, int* __restrict__ bcur, float* __restrict__ ewPart,
    int* __restrict__ counts, unsigned int* __restrict__ pairs,
    uint2* __restrict__ staging, float* __restrict__ out)
{
    cg::grid_group grid = cg::this_grid();
    phase1(ei, ew, bcur, ewPart, staging, blockIdx.x, gridDim.x);
    grid.sync();
    phase2(staging, bcur, ewPart, pairs, counts, scal, blockIdx.x, gridDim.x);
    grid.sync();
    int wid = blockIdx.x * 4 + (threadIdx.x >> 6);
    phase3((const unsigned int*)xph, a_src, a_dst, counts, pairs, scal,
           bias, gamma, beta, out, wid, gridDim.x * 4);
}

// non-cooperative fallbacks (same phases, separate dispatches)
__global__ __launch_bounds__(TPB) void k_p1(const int* __restrict__ ei, const float* __restrict__ ew,
                                            int* __restrict__ bcur, float* __restrict__ ewPart,
                                            uint2* __restrict__ staging)
{ phase1(ei, ew, bcur, ewPart, staging, blockIdx.x, gridDim.x); }

__global__ __launch_bounds__(TPB) void k_p2(const uint2* __restrict__ staging, const int* __restrict__ bcur,
                                            const float* __restrict__ ewPart, unsigned int* __restrict__ pairs,
                                            int* __restrict__ counts, float* __restrict__ scal)
{ phase2(staging, bcur, ewPart, pairs, counts, scal, blockIdx.x, gridDim.x); }

__global__ __launch_bounds__(TPB) void k_p3(const unsigned short* __restrict__ xph, const float* __restrict__ a_src,
                                            const float* __restrict__ a_dst, const int* __restrict__ counts,
                                            const unsigned int* __restrict__ pairs, const float* __restrict__ scal,
                                            const float* __restrict__ bias, const float* __restrict__ gamma,
                                            const float* __restrict__ beta, float* __restrict__ out)
{
    int wid = blockIdx.x * 4 + (threadIdx.x >> 6);
    phase3((const unsigned int*)xph, a_src, a_dst, counts, pairs, scal,
           bias, gamma, beta, out, wid, gridDim.x * 4);
}

extern "C" void kernel_launch(void* const* d_in, const int* in_sizes, int n_in,
                              void* d_out, int out_size, void* d_ws, size_t ws_size,
                              hipStream_t stream) {
    const float* x        = (const float*)d_in[0];
    const int*   ei       = (const int*)d_in[1];
    const float* ew       = (const float*)d_in[2];
    const float* W        = (const float*)d_in[3];
    const float* att_src  = (const float*)d_in[4];
    const float* att_dst  = (const float*)d_in[5];
    const float* W_edge   = (const float*)d_in[6];
    const float* att_edge = (const float*)d_in[7];
    const float* bias     = (const float*)d_in[8];
    const float* gamma    = (const float*)d_in[9];
    const float* beta     = (const float*)d_in[10];
    float* out = (float*)d_out;

    char* ws = (char*)d_ws;
    float* scal      = (float*)(ws + OFF_SCAL);
    int*   bcur      = (int*)(ws + OFF_BCUR);
    float* ewPart    = (float*)(ws + OFF_EWPART);
    int*   counts    = (int*)(ws + OFF_COUNTS);
    float* a_src     = (float*)(ws + OFF_ASRC);
    float* a_dst     = (float*)(ws + OFF_ADST);
    unsigned short* xph = (unsigned short*)(ws + OFF_XPH);
    unsigned int* pairs = (unsigned int*)(ws + OFF_PAIRS);
    uint2* staging   = (uint2*)(ws + OFF_STAGE);

    k_gemm<<<(N_NODES + 63) / 64, 256, 0, stream>>>(x, W, att_src, att_dst, W_edge, att_edge,
                                                    xph, a_src, a_dst, scal, bcur);

    int occ = 0;
    bool coop_ok = false;
    if (hipOccupancyMaxActiveBlocksPerMultiprocessor(&occ, (const void*)k_fused, TPB, 0)
            == hipSuccess && occ >= 1) {
        int grid = occ * 256;
        if (grid > 2048) grid = 2048;
        void* kargs[] = {
            (void*)&ei, (void*)&ew, (void*)&xph, (void*)&a_src, (void*)&a_dst,
            (void*)&bias, (void*)&gamma, (void*)&beta, (void*)&scal, (void*)&bcur,
            (void*)&ewPart, (void*)&counts, (void*)&pairs, (void*)&staging, (void*)&out
        };
        coop_ok = (hipLaunchCooperativeKernel((void*)k_fused, dim3(grid), dim3(TPB),
                                              kargs, 0, stream) == hipSuccess);
    }
    if (!coop_ok) {
        (void)hipGetLastError();   // clear sticky error from rejected coop launch
        k_p1<<<NCH, TPB, 0, stream>>>(ei, ew, bcur, ewPart, staging);
        k_p2<<<NBK, TPB, 0, stream>>>(staging, bcur, ewPart, pairs, counts, scal);
        k_p3<<<12500, TPB, 0, stream>>>(xph, a_src, a_dst, counts, pairs, scal,
                                        bias, gamma, beta, out);
    }
}

// Round 12
// 260.039 us; speedup vs baseline: 2.8576x; 2.4307x over previous
//
#include <hip/hip_runtime.h>
#include <hip/hip_fp16.h>
#include <cstddef>

#define N_NODES 50000
#define E_EDGES 1600000
#define NEG_SLOPE 0.2f
#define LN_EPS 1e-5f
#define LOG2E 1.4426950408889634f
#define PAD 96        // max in-degree; Poisson(32) -> P(deg>96) ~ 1e-19

#define NBK 196       // dst buckets of 256 nodes
#define BCAP 10240    // entries per bucket (mean 8192, >20 sigma headroom)
#define PCH 4096      // edges per partition chunk
#define NCH 391       // ceil(E/PCH)
#define TPB 256

// ---------------- workspace layout (bytes) ----------------
// scal[0] = ew_sum, scal[4..7] = K[h]
#define OFF_SCAL    0u
#define OFF_BCUR    256u                       // NBK ints
#define OFF_EWPART  2048u                      // NCH floats
#define OFF_COUNTS  8192u                      // N ints -> 208,192
#define OFF_ASRC    208256u                    // N*4 floats -> 1,008,256
#define OFF_ADST    1008256u                   // N*4 floats -> 1,808,256
#define OFF_XPH     1808256u                   // N*128 halfs -> 14,608,256
#define OFF_PAIRS   14608256u                  // N*PAD uints -> 33,808,256
#define OFF_STAGE   33808256u                  // NBK*BCAP uint2 -> 49,864,576

__device__ __forceinline__ float lrelu(float x) { return x > 0.f ? x : NEG_SLOPE * x; }

__device__ __forceinline__ float sel4(float4 v, int h) {
    float ab = (h & 1) ? v.y : v.x;
    float cd = (h & 1) ? v.w : v.z;
    return (h & 2) ? cd : ab;
}

__device__ __forceinline__ float4 fma4(float s, float4 a, float4 c) {
    c.x = fmaf(s, a.x, c.x); c.y = fmaf(s, a.y, c.y);
    c.z = fmaf(s, a.z, c.z); c.w = fmaf(s, a.w, c.w);
    return c;
}

// xp = x @ W (stored fp16); a_src[n,h], a_dst[n,h]; block 0 zeroes bcur + K[h].
__global__ __launch_bounds__(256) void k_gemm(const float* __restrict__ x, const float* __restrict__ W,
                                              const float* __restrict__ att_src, const float* __restrict__ att_dst,
                                              const float* __restrict__ W_edge, const float* __restrict__ att_edge,
                                              unsigned short* __restrict__ xph, float* __restrict__ a_src,
                                              float* __restrict__ a_dst, float* __restrict__ scal,
                                              int* __restrict__ bcur) {
    __shared__ float sx[64 * 128];  // 32 KB
    __shared__ float sW[64 * 128];  // 32 KB
    int t = threadIdx.x;
    if (blockIdx.x == 0) {
        if (t < NBK) bcur[t] = 0;
        if (t < 128) {
            float p = W_edge[t] * att_edge[t];
            #pragma unroll
            for (int off = 16; off; off >>= 1) p += __shfl_down(p, off, 32);
            if ((t & 31) == 0) scal[4 + (t >> 5)] = p;
        }
    }
    int r0 = blockIdx.x * 64;
    int tc = t & 31;
    int tr = t >> 5;

    for (int i = t; i < 2048; i += 256) {
        int row = i >> 5;
        float4 v = make_float4(0.f, 0.f, 0.f, 0.f);
        if (r0 + row < N_NODES) v = ((const float4*)x)[(size_t)(r0 + row) * 32 + (i & 31)];
        ((float4*)sx)[i] = v;
    }

    float4 acc[8];
    #pragma unroll
    for (int r = 0; r < 8; r++) acc[r] = make_float4(0.f, 0.f, 0.f, 0.f);

    for (int kc = 0; kc < 128; kc += 64) {
        __syncthreads();
        for (int i = t; i < 2048; i += 256)
            ((float4*)sW)[i] = ((const float4*)W)[(size_t)kc * 32 + i];
        __syncthreads();
        #pragma unroll 4
        for (int k4 = 0; k4 < 16; k4++) {
            float4 w0 = ((float4*)sW)[(k4 * 4 + 0) * 32 + tc];
            float4 w1 = ((float4*)sW)[(k4 * 4 + 1) * 32 + tc];
            float4 w2 = ((float4*)sW)[(k4 * 4 + 2) * 32 + tc];
            float4 w3 = ((float4*)sW)[(k4 * 4 + 3) * 32 + tc];
            #pragma unroll
            for (int r = 0; r < 8; r++) {
                float4 xv = ((float4*)sx)[(tr * 8 + r) * 32 + (kc >> 2) + k4];
                acc[r] = fma4(xv.x, w0, acc[r]);
                acc[r] = fma4(xv.y, w1, acc[r]);
                acc[r] = fma4(xv.z, w2, acc[r]);
                acc[r] = fma4(xv.w, w3, acc[r]);
            }
        }
    }

    float4 s4 = ((const float4*)att_src)[tc];
    float4 d4 = ((const float4*)att_dst)[tc];
    int h = tc >> 3;
    #pragma unroll
    for (int r = 0; r < 8; r++) {
        int row = r0 + tr * 8 + r;
        if (row < N_NODES) {
            __half2 h01 = __floats2half2_rn(acc[r].x, acc[r].y);
            __half2 h23 = __floats2half2_rn(acc[r].z, acc[r].w);
            uint2 pk;
            pk.x = *(unsigned int*)&h01;
            pk.y = *(unsigned int*)&h23;
            ((uint2*)xph)[(size_t)row * 32 + tc] = pk;
            float ps = acc[r].x * s4.x + acc[r].y * s4.y + acc[r].z * s4.z + acc[r].w * s4.w;
            float pd = acc[r].x * d4.x + acc[r].y * d4.y + acc[r].z * d4.z + acc[r].w * d4.w;
            ps += __shfl_down(ps, 4, 8); ps += __shfl_down(ps, 2, 8); ps += __shfl_down(ps, 1, 8);
            pd += __shfl_down(pd, 4, 8); pd += __shfl_down(pd, 2, 8); pd += __shfl_down(pd, 1, 8);
            if ((tc & 7) == 0) {
                a_src[(size_t)row * 4 + h] = ps;
                a_dst[(size_t)row * 4 + h] = pd;
            }
        }
    }
}

// pass 1 (round-8 proven): partition edges into 256-node dst buckets.
__global__ __launch_bounds__(256) void k_p1(const int* __restrict__ ei, const float* __restrict__ ew,
                                            int* __restrict__ bcur, uint2* __restrict__ staging,
                                            float* __restrict__ ewPart) {
    int t = threadIdx.x;
    __shared__ int cnt[NBK];
    __shared__ int gbase[NBK];
    __shared__ float wred[4];
    for (int i = t; i < NBK; i += 256) cnt[i] = 0;
    __syncthreads();

    int e0 = blockIdx.x * PCH;
    int lr[16];
    float s_ew = 0.f;
    #pragma unroll
    for (int i = 0; i < 16; i++) {
        int e = e0 + i * 256 + t;
        lr[i] = 0;
        if (e < E_EDGES) {
            int d = ei[E_EDGES + e];
            s_ew += ew[e];
            lr[i] = atomicAdd(&cnt[d >> 8], 1);
        }
    }
    #pragma unroll
    for (int off = 32; off; off >>= 1) s_ew += __shfl_down(s_ew, off, 64);
    if ((t & 63) == 0) wred[t >> 6] = s_ew;
    __syncthreads();
    if (t == 0) ewPart[blockIdx.x] = wred[0] + wred[1] + wred[2] + wred[3];
    for (int i = t; i < NBK; i += 256) gbase[i] = atomicAdd(&bcur[i], cnt[i]);
    __syncthreads();

    #pragma unroll
    for (int i = 0; i < 16; i++) {
        int e = e0 + i * 256 + t;
        if (e < E_EDGES) {
            int s = ei[e];
            int d = ei[E_EDGES + e];
            float w = ew[e];
            int b = d >> 8;
            uint2 ent;
            ent.x = (unsigned int)s |
                    ((unsigned int)__half_as_ushort(__float2half_rn(w)) << 16);
            ent.y = (unsigned int)d;
            staging[(size_t)b * BCAP + gbase[b] + lr[i]] = ent;
        }
    }
}

// pass 2 (round-8 proven): bucket -> padded CSR + counts; block 0 also ew total.
__global__ __launch_bounds__(256) void k_p2(const uint2* __restrict__ staging,
                                            const int* __restrict__ bcur,
                                            const float* __restrict__ ewPart,
                                            unsigned int* __restrict__ pairs,
                                            int* __restrict__ counts, float* __restrict__ scal) {
    int b = blockIdx.x, t = threadIdx.x;
    __shared__ int cnt2[256];
    __shared__ float wr2[4];
    if (b == 0) {
        float s = 0.f;
        for (int i = t; i < NCH; i += 256) s += ewPart[i];
        #pragma unroll
        for (int off = 32; off; off >>= 1) s += __shfl_down(s, off, 64);
        if ((t & 63) == 0) wr2[t >> 6] = s;
    }
    cnt2[t] = 0;
    __syncthreads();
    if (b == 0 && t == 0) scal[0] = wr2[0] + wr2[1] + wr2[2] + wr2[3];
    int tot = bcur[b];
    const uint2* sg = staging + (size_t)b * BCAP;
    for (int i = t; i < tot; i += 256) {
        uint2 ent = sg[i];
        int d = (int)ent.y;
        int r = atomicAdd(&cnt2[d & 255], 1);
        pairs[(size_t)d * PAD + r] = ent.x;
    }
    __syncthreads();
    int n = (b << 8) + t;
    if (n < N_NODES) counts[n] = cnt2[t];
}

// pass 3: wave-per-node aggregate, NO barriers, fully-unrolled 16-edge gather.
// Out-of-range lanes carry alpha=0, s=n (padded gathers hit the hot self row).
__global__ __launch_bounds__(256) void k_p3(const unsigned int* __restrict__ xpu,
                                            const float* __restrict__ a_src,
                                            const float* __restrict__ a_dst,
                                            const int* __restrict__ counts,
                                            const unsigned int* __restrict__ pairs,
                                            const float* __restrict__ scal,
                                            const float* __restrict__ bias,
                                            const float* __restrict__ gamma,
                                            const float* __restrict__ beta,
                                            float* __restrict__ out) {
    int lane = threadIdx.x & 63;
    int wid = blockIdx.x * 4 + (threadIdx.x >> 6);
    int h = lane >> 4;        // head for this lane's channel pair
    int em = lane & 15;       // edge slot within a 16-edge batch
    int shb = lane & 48;      // shuffle base: this head's alpha group
    float4 K = *(const float4*)(scal + 4);
    float Kh = sel4(K, h);
    float mean_ew = scal[0] * (1.0f / E_EDGES);

    int n = wid;
    if (n >= N_NODES) return;
    {
        int cnt = counts[n];
        float4 ad4 = *(const float4*)(a_dst + (size_t)4 * n);
        float4 as4 = *(const float4*)(a_src + (size_t)4 * n);
        float adh = sel4(ad4, h);
        float aself = exp2f(lrelu(sel4(as4, h) + adh + Kh * mean_ew) * LOG2E);

        unsigned int pv = xpu[(size_t)n * 64 + lane];   // channels 2l, 2l+1
        float2 f = __half22float2(*(__half2*)&pv);
        float acc0 = aself * f.x, acc1 = aself * f.y;
        float den = 0.f;

        for (int base = 0; base < cnt; base += 16) {
            int e = base + em;
            float alpha = 0.f;
            int s = n;
            if (e < cnt) {
                unsigned int pk = pairs[(size_t)n * PAD + e];
                s = (int)(pk & 0xFFFFu);
                float w = __half2float(__ushort_as_half((unsigned short)(pk >> 16)));
                float4 av = *(const float4*)(a_src + (size_t)4 * s);
                alpha = exp2f(lrelu(sel4(av, h) + adh + Kh * w) * LOG2E);
            }
            den += alpha;
            #pragma unroll
            for (int j = 0; j < 16; j++) {
                int sj   = __shfl(s, shb + j, 64);
                float aj = __shfl(alpha, shb + j, 64);
                unsigned int p2 = xpu[(size_t)sj * 64 + lane];
                float2 g = __half22float2(*(__half2*)&p2);
                acc0 = fmaf(aj, g.x, acc0);
                acc1 = fmaf(aj, g.y, acc1);
            }
        }
        // reduce den across the 16 lanes sharing this head
        den += __shfl_xor(den, 1, 64);
        den += __shfl_xor(den, 2, 64);
        den += __shfl_xor(den, 4, 64);
        den += __shfl_xor(den, 8, 64);
        den += aself;

        float inv = 1.0f / (den + 1e-16f);
        float2 b2 = ((const float2*)bias)[lane];
        float y0 = fmaf(acc0, inv, b2.x);
        float y1 = fmaf(acc1, inv, b2.y);

        // LayerNorm over 128 channels (2 per lane) via full-wave xor reduce
        float s1 = y0 + y1;
        #pragma unroll
        for (int off = 1; off < 64; off <<= 1) s1 += __shfl_xor(s1, off, 64);
        float mu = s1 * (1.f / 128.f);
        float d0 = y0 - mu, d1 = y1 - mu;
        float s2 = d0 * d0 + d1 * d1;
        #pragma unroll
        for (int off = 1; off < 64; off <<= 1) s2 += __shfl_xor(s2, off, 64);
        float rstd = rsqrtf(s2 * (1.f / 128.f) + LN_EPS);
        float2 g2 = ((const float2*)gamma)[lane];
        float2 be2 = ((const float2*)beta)[lane];
        float o0 = fmaf(d0 * rstd, g2.x, be2.x);
        float o1 = fmaf(d1 * rstd, g2.y, be2.y);
        o0 = o0 > 0.f ? o0 : expm1f(o0);
        o1 = o1 > 0.f ? o1 : expm1f(o1);
        float2 o; o.x = o0; o.y = o1;
        ((float2*)out)[(size_t)n * 64 + lane] = o;
    }
}

extern "C" void kernel_launch(void* const* d_in, const int* in_sizes, int n_in,
                              void* d_out, int out_size, void* d_ws, size_t ws_size,
                              hipStream_t stream) {
    const float* x        = (const float*)d_in[0];
    const int*   ei       = (const int*)d_in[1];
    const float* ew       = (const float*)d_in[2];
    const float* W        = (const float*)d_in[3];
    const float* att_src  = (const float*)d_in[4];
    const float* att_dst  = (const float*)d_in[5];
    const float* W_edge   = (const float*)d_in[6];
    const float* att_edge = (const float*)d_in[7];
    const float* bias     = (const float*)d_in[8];
    const float* gamma    = (const float*)d_in[9];
    const float* beta     = (const float*)d_in[10];
    float* out = (float*)d_out;

    char* ws = (char*)d_ws;
    float* scal      = (float*)(ws + OFF_SCAL);
    int*   bcur      = (int*)(ws + OFF_BCUR);
    float* ewPart    = (float*)(ws + OFF_EWPART);
    int*   counts    = (int*)(ws + OFF_COUNTS);
    float* a_src     = (float*)(ws + OFF_ASRC);
    float* a_dst     = (float*)(ws + OFF_ADST);
    unsigned short* xph = (unsigned short*)(ws + OFF_XPH);
    unsigned int* pairs = (unsigned int*)(ws + OFF_PAIRS);
    uint2* staging   = (uint2*)(ws + OFF_STAGE);

    k_gemm<<<(N_NODES + 63) / 64, 256, 0, stream>>>(x, W, att_src, att_dst, W_edge, att_edge,
                                                    xph, a_src, a_dst, scal, bcur);
    k_p1<<<NCH, TPB, 0, stream>>>(ei, ew, bcur, staging, ewPart);
    k_p2<<<NBK, TPB, 0, stream>>>(staging, bcur, ewPart, pairs, counts, scal);
    k_p3<<<12500, TPB, 0, stream>>>((const unsigned int*)xph, a_src, a_dst, counts, pairs, scal,
                                    bias, gamma, beta, out);
}

// Round 13
// 231.986 us; speedup vs baseline: 3.2032x; 1.1209x over previous
//
#include <hip/hip_runtime.h>
#include <hip/hip_fp16.h>
#include <cstddef>

#define N_NODES 50000
#define E_EDGES 1600000
#define NEG_SLOPE 0.2f
#define LN_EPS 1e-5f
#define LOG2E 1.4426950408889634f
#define PAD 96        // max in-degree; Poisson(32) -> P(deg>96) ~ 1e-19

#define NBK 196       // dst buckets of 256 nodes
#define BCAP 10240    // entries per bucket (mean 8192, >20 sigma headroom)
#define PCH 4096      // edges per partition chunk
#define NCH 391       // ceil(E/PCH)
#define TPB 256

// ---------------- workspace layout (bytes) ----------------
// scal[0] = ew_sum, scal[4..7] = K[h]
#define OFF_SCAL    0u
#define OFF_BCUR    256u                       // NBK ints
#define OFF_EWPART  2048u                      // NCH floats
#define OFF_COUNTS  8192u                      // N ints -> 208,192
#define OFF_ASRC    208256u                    // N*4 floats -> 1,008,256
#define OFF_ADST    1008256u                   // N*4 floats -> 1,808,256
#define OFF_XPH     1808256u                   // N*128 halfs -> 14,608,256
#define OFF_PAIRS   14608256u                  // N*PAD uints -> 33,808,256
#define OFF_STAGE   33808256u                  // NBK*BCAP uint2 -> 49,864,576

__device__ __forceinline__ float lrelu(float x) { return x > 0.f ? x : NEG_SLOPE * x; }

__device__ __forceinline__ float sel4(float4 v, int h) {
    float ab = (h & 1) ? v.y : v.x;
    float cd = (h & 1) ? v.w : v.z;
    return (h & 2) ? cd : ab;
}

__device__ __forceinline__ float4 fma4(float s, float4 a, float4 c) {
    c.x = fmaf(s, a.x, c.x); c.y = fmaf(s, a.y, c.y);
    c.z = fmaf(s, a.z, c.z); c.w = fmaf(s, a.w, c.w);
    return c;
}

// xp = x @ W (stored fp16); a_src[n,h], a_dst[n,h]; block 0 zeroes bcur + K[h].
// 32 rows/block, 32 KB LDS (16 x + 16 W-chunk) -> ~5 blocks/CU resident.
__global__ __launch_bounds__(256, 5) void k_gemm(const float* __restrict__ x, const float* __restrict__ W,
                                                 const float* __restrict__ att_src, const float* __restrict__ att_dst,
                                                 const float* __restrict__ W_edge, const float* __restrict__ att_edge,
                                                 unsigned short* __restrict__ xph, float* __restrict__ a_src,
                                                 float* __restrict__ a_dst, float* __restrict__ scal,
                                                 int* __restrict__ bcur) {
    __shared__ float sx[32 * 128];  // 16 KB
    __shared__ float sW[32 * 128];  // 16 KB
    int t = threadIdx.x;
    if (blockIdx.x == 0) {
        if (t < NBK) bcur[t] = 0;
        if (t < 128) {
            float p = W_edge[t] * att_edge[t];
            #pragma unroll
            for (int off = 16; off; off >>= 1) p += __shfl_down(p, off, 32);
            if ((t & 31) == 0) scal[4 + (t >> 5)] = p;
        }
    }
    int r0 = blockIdx.x * 32;
    int tc = t & 31;   // col group: cols tc*4..tc*4+3
    int tr = t >> 5;   // row group: rows tr*4..tr*4+3

    for (int i = t; i < 1024; i += 256) {
        int row = i >> 5;
        float4 v = make_float4(0.f, 0.f, 0.f, 0.f);
        if (r0 + row < N_NODES) v = ((const float4*)x)[(size_t)(r0 + row) * 32 + (i & 31)];
        ((float4*)sx)[i] = v;
    }

    float4 acc[4];
    #pragma unroll
    for (int r = 0; r < 4; r++) acc[r] = make_float4(0.f, 0.f, 0.f, 0.f);

    for (int kc = 0; kc < 128; kc += 32) {
        __syncthreads();
        for (int i = t; i < 1024; i += 256)
            ((float4*)sW)[i] = ((const float4*)W)[(size_t)kc * 32 + i];
        __syncthreads();
        #pragma unroll 4
        for (int k4 = 0; k4 < 8; k4++) {
            float4 w0 = ((float4*)sW)[(k4 * 4 + 0) * 32 + tc];
            float4 w1 = ((float4*)sW)[(k4 * 4 + 1) * 32 + tc];
            float4 w2 = ((float4*)sW)[(k4 * 4 + 2) * 32 + tc];
            float4 w3 = ((float4*)sW)[(k4 * 4 + 3) * 32 + tc];
            #pragma unroll
            for (int r = 0; r < 4; r++) {
                float4 xv = ((float4*)sx)[(tr * 4 + r) * 32 + (kc >> 2) + k4];
                acc[r] = fma4(xv.x, w0, acc[r]);
                acc[r] = fma4(xv.y, w1, acc[r]);
                acc[r] = fma4(xv.z, w2, acc[r]);
                acc[r] = fma4(xv.w, w3, acc[r]);
            }
        }
    }

    float4 s4 = ((const float4*)att_src)[tc];
    float4 d4 = ((const float4*)att_dst)[tc];
    int h = tc >> 3;
    #pragma unroll
    for (int r = 0; r < 4; r++) {
        int row = r0 + tr * 4 + r;
        if (row < N_NODES) {
            __half2 h01 = __floats2half2_rn(acc[r].x, acc[r].y);
            __half2 h23 = __floats2half2_rn(acc[r].z, acc[r].w);
            uint2 pk;
            pk.x = *(unsigned int*)&h01;
            pk.y = *(unsigned int*)&h23;
            ((uint2*)xph)[(size_t)row * 32 + tc] = pk;
            float ps = acc[r].x * s4.x + acc[r].y * s4.y + acc[r].z * s4.z + acc[r].w * s4.w;
            float pd = acc[r].x * d4.x + acc[r].y * d4.y + acc[r].z * d4.z + acc[r].w * d4.w;
            ps += __shfl_down(ps, 4, 8); ps += __shfl_down(ps, 2, 8); ps += __shfl_down(ps, 1, 8);
            pd += __shfl_down(pd, 4, 8); pd += __shfl_down(pd, 2, 8); pd += __shfl_down(pd, 1, 8);
            if ((tc & 7) == 0) {
                a_src[(size_t)row * 4 + h] = ps;
                a_dst[(size_t)row * 4 + h] = pd;
            }
        }
    }
}

// pass 1 (round-8 proven): partition edges into 256-node dst buckets.
__global__ __launch_bounds__(256) void k_p1(const int* __restrict__ ei, const float* __restrict__ ew,
                                            int* __restrict__ bcur, uint2* __restrict__ staging,
                                            float* __restrict__ ewPart) {
    int t = threadIdx.x;
    __shared__ int cnt[NBK];
    __shared__ int gbase[NBK];
    __shared__ float wred[4];
    for (int i = t; i < NBK; i += 256) cnt[i] = 0;
    __syncthreads();

    int e0 = blockIdx.x * PCH;
    int lr[16];
    float s_ew = 0.f;
    #pragma unroll
    for (int i = 0; i < 16; i++) {
        int e = e0 + i * 256 + t;
        lr[i] = 0;
        if (e < E_EDGES) {
            int d = ei[E_EDGES + e];
            s_ew += ew[e];
            lr[i] = atomicAdd(&cnt[d >> 8], 1);
        }
    }
    #pragma unroll
    for (int off = 32; off; off >>= 1) s_ew += __shfl_down(s_ew, off, 64);
    if ((t & 63) == 0) wred[t >> 6] = s_ew;
    __syncthreads();
    if (t == 0) ewPart[blockIdx.x] = wred[0] + wred[1] + wred[2] + wred[3];
    for (int i = t; i < NBK; i += 256) gbase[i] = atomicAdd(&bcur[i], cnt[i]);
    __syncthreads();

    #pragma unroll
    for (int i = 0; i < 16; i++) {
        int e = e0 + i * 256 + t;
        if (e < E_EDGES) {
            int s = ei[e];
            int d = ei[E_EDGES + e];
            float w = ew[e];
            int b = d >> 8;
            uint2 ent;
            ent.x = (unsigned int)s |
                    ((unsigned int)__half_as_ushort(__float2half_rn(w)) << 16);
            ent.y = (unsigned int)d;
            staging[(size_t)b * BCAP + gbase[b] + lr[i]] = ent;
        }
    }
}

// pass 2 (round-8 proven): bucket -> padded CSR + counts; block 0 also ew total.
__global__ __launch_bounds__(256) void k_p2(const uint2* __restrict__ staging,
                                            const int* __restrict__ bcur,
                                            const float* __restrict__ ewPart,
                                            unsigned int* __restrict__ pairs,
                                            int* __restrict__ counts, float* __restrict__ scal) {
    int b = blockIdx.x, t = threadIdx.x;
    __shared__ int cnt2[256];
    __shared__ float wr2[4];
    if (b == 0) {
        float s = 0.f;
        for (int i = t; i < NCH; i += 256) s += ewPart[i];
        #pragma unroll
        for (int off = 32; off; off >>= 1) s += __shfl_down(s, off, 64);
        if ((t & 63) == 0) wr2[t >> 6] = s;
    }
    cnt2[t] = 0;
    __syncthreads();
    if (b == 0 && t == 0) scal[0] = wr2[0] + wr2[1] + wr2[2] + wr2[3];
    int tot = bcur[b];
    const uint2* sg = staging + (size_t)b * BCAP;
    for (int i = t; i < tot; i += 256) {
        uint2 ent = sg[i];
        int d = (int)ent.y;
        int r = atomicAdd(&cnt2[d & 255], 1);
        pairs[(size_t)d * PAD + r] = ent.x;
    }
    __syncthreads();
    int n = (b << 8) + t;
    if (n < N_NODES) counts[n] = cnt2[t];
}

// pass 3: wave-per-node aggregate, NO barriers, fully-unrolled 16-edge gather.
// Out-of-range lanes carry alpha=0, s=n (padded gathers hit the hot self row).
__global__ __launch_bounds__(256) void k_p3(const unsigned int* __restrict__ xpu,
                                            const float* __restrict__ a_src,
                                            const float* __restrict__ a_dst,
                                            const int* __restrict__ counts,
                                            const unsigned int* __restrict__ pairs,
                                            const float* __restrict__ scal,
                                            const float* __restrict__ bias,
                                            const float* __restrict__ gamma,
                                            const float* __restrict__ beta,
                                            float* __restrict__ out) {
    int lane = threadIdx.x & 63;
    int wid = blockIdx.x * 4 + (threadIdx.x >> 6);
    int h = lane >> 4;        // head for this lane's channel pair
    int em = lane & 15;       // edge slot within a 16-edge batch
    int shb = lane & 48;      // shuffle base: this head's alpha group
    float4 K = *(const float4*)(scal + 4);
    float Kh = sel4(K, h);
    float mean_ew = scal[0] * (1.0f / E_EDGES);

    int n = wid;
    if (n >= N_NODES) return;
    {
        int cnt = counts[n];
        float4 ad4 = *(const float4*)(a_dst + (size_t)4 * n);
        float4 as4 = *(const float4*)(a_src + (size_t)4 * n);
        float adh = sel4(ad4, h);
        float aself = exp2f(lrelu(sel4(as4, h) + adh + Kh * mean_ew) * LOG2E);

        unsigned int pv = xpu[(size_t)n * 64 + lane];   // channels 2l, 2l+1
        float2 f = __half22float2(*(__half2*)&pv);
        float acc0 = aself * f.x, acc1 = aself * f.y;
        float den = 0.f;

        for (int base = 0; base < cnt; base += 16) {
            int e = base + em;
            float alpha = 0.f;
            int s = n;
            if (e < cnt) {
                unsigned int pk = pairs[(size_t)n * PAD + e];
                s = (int)(pk & 0xFFFFu);
                float w = __half2float(__ushort_as_half((unsigned short)(pk >> 16)));
                float4 av = *(const float4*)(a_src + (size_t)4 * s);
                alpha = exp2f(lrelu(sel4(av, h) + adh + Kh * w) * LOG2E);
            }
            den += alpha;
            #pragma unroll
            for (int j = 0; j < 16; j++) {
                int sj   = __shfl(s, shb + j, 64);
                float aj = __shfl(alpha, shb + j, 64);
                unsigned int p2 = xpu[(size_t)sj * 64 + lane];
                float2 g = __half22float2(*(__half2*)&p2);
                acc0 = fmaf(aj, g.x, acc0);
                acc1 = fmaf(aj, g.y, acc1);
            }
        }
        // reduce den across the 16 lanes sharing this head
        den += __shfl_xor(den, 1, 64);
        den += __shfl_xor(den, 2, 64);
        den += __shfl_xor(den, 4, 64);
        den += __shfl_xor(den, 8, 64);
        den += aself;

        float inv = 1.0f / (den + 1e-16f);
        float2 b2 = ((const float2*)bias)[lane];
        float y0 = fmaf(acc0, inv, b2.x);
        float y1 = fmaf(acc1, inv, b2.y);

        // LayerNorm over 128 channels (2 per lane) via full-wave xor reduce
        float s1 = y0 + y1;
        #pragma unroll
        for (int off = 1; off < 64; off <<= 1) s1 += __shfl_xor(s1, off, 64);
        float mu = s1 * (1.f / 128.f);
        float d0 = y0 - mu, d1 = y1 - mu;
        float s2 = d0 * d0 + d1 * d1;
        #pragma unroll
        for (int off = 1; off < 64; off <<= 1) s2 += __shfl_xor(s2, off, 64);
        float rstd = rsqrtf(s2 * (1.f / 128.f) + LN_EPS);
        float2 g2 = ((const float2*)gamma)[lane];
        float2 be2 = ((const float2*)beta)[lane];
        float o0 = fmaf(d0 * rstd, g2.x, be2.x);
        float o1 = fmaf(d1 * rstd, g2.y, be2.y);
        o0 = o0 > 0.f ? o0 : expm1f(o0);
        o1 = o1 > 0.f ? o1 : expm1f(o1);
        float2 o; o.x = o0; o.y = o1;
        ((float2*)out)[(size_t)n * 64 + lane] = o;
    }
}

extern "C" void kernel_launch(void* const* d_in, const int* in_sizes, int n_in,
                              void* d_out, int out_size, void* d_ws, size_t ws_size,
                              hipStream_t stream) {
    const float* x        = (const float*)d_in[0];
    const int*   ei       = (const int*)d_in[1];
    const float* ew       = (const float*)d_in[2];
    const float* W        = (const float*)d_in[3];
    const float* att_src  = (const float*)d_in[4];
    const float* att_dst  = (const float*)d_in[5];
    const float* W_edge   = (const float*)d_in[6];
    const float* att_edge = (const float*)d_in[7];
    const float* bias     = (const float*)d_in[8];
    const float* gamma    = (const float*)d_in[9];
    const float* beta     = (const float*)d_in[10];
    float* out = (float*)d_out;

    char* ws = (char*)d_ws;
    float* scal      = (float*)(ws + OFF_SCAL);
    int*   bcur      = (int*)(ws + OFF_BCUR);
    float* ewPart    = (float*)(ws + OFF_EWPART);
    int*   counts    = (int*)(ws + OFF_COUNTS);
    float* a_src     = (float*)(ws + OFF_ASRC);
    float* a_dst     = (float*)(ws + OFF_ADST);
    unsigned short* xph = (unsigned short*)(ws + OFF_XPH);
    unsigned int* pairs = (unsigned int*)(ws + OFF_PAIRS);
    uint2* staging   = (uint2*)(ws + OFF_STAGE);

    k_gemm<<<(N_NODES + 31) / 32, 256, 0, stream>>>(x, W, att_src, att_dst, W_edge, att_edge,
                                                    xph, a_src, a_dst, scal, bcur);
    k_p1<<<NCH, TPB, 0, stream>>>(ei, ew, bcur, staging, ewPart);
    k_p2<<<NBK, TPB, 0, stream>>>(staging, bcur, ewPart, pairs, counts, scal);
    k_p3<<<12500, TPB, 0, stream>>>((const unsigned int*)xph, a_src, a_dst, counts, pairs, scal,
                                    bias, gamma, beta, out);
}

// Round 14
// 215.504 us; speedup vs baseline: 3.4482x; 1.0765x over previous
//
#include <hip/hip_runtime.h>
#include <hip/hip_fp16.h>
#include <cstddef>

#define N_NODES 50000
#define E_EDGES 1600000
#define NEG_SLOPE 0.2f
#define LN_EPS 1e-5f
#define LOG2E 1.4426950408889634f
#define PAD 96        // max in-degree; Poisson(32) -> P(deg>96) ~ 1e-19

#define NBK 196       // dst buckets of 256 nodes
#define BCAP 10240    // entries per bucket (mean 8192, >20 sigma headroom)
#define PCH 4096      // edges per partition chunk
#define NCH 391       // ceil(E/PCH)
#define NGB 1563      // gemm blocks: ceil(N/32)
#define TPB 256

// ---------------- workspace layout (bytes) ----------------
// scal[0] = ew_sum, scal[4..7] = K[h]
#define OFF_SCAL    0u
#define OFF_BCUR    256u                       // NBK ints
#define OFF_EWPART  2048u                      // NCH floats
#define OFF_COUNTS  8192u                      // N ints -> 208,192
#define OFF_ASRC    208256u                    // N*4 floats -> 1,008,256
#define OFF_ADST    1008256u                   // N*4 floats -> 1,808,256
#define OFF_XPH     1808256u                   // N*128 halfs -> 14,608,256
#define OFF_PAIRS   14608256u                  // N*PAD uints -> 33,808,256
#define OFF_STAGE   33808256u                  // NBK*BCAP uint2 -> 49,864,576

__device__ __forceinline__ float lrelu(float x) { return x > 0.f ? x : NEG_SLOPE * x; }

__device__ __forceinline__ float sel4(float4 v, int h) {
    float ab = (h & 1) ? v.y : v.x;
    float cd = (h & 1) ? v.w : v.z;
    return (h & 2) ? cd : ab;
}

__device__ __forceinline__ float4 fma4(float s, float4 a, float4 c) {
    c.x = fmaf(s, a.x, c.x); c.y = fmaf(s, a.y, c.y);
    c.z = fmaf(s, a.z, c.z); c.w = fmaf(s, a.w, c.w);
    return c;
}

// fused independent work: blocks [0,NCH) = edge partition (p1);
// blocks [NCH, NCH+NGB) = node GEMM. bcur pre-zeroed via memsetAsync.
__global__ __launch_bounds__(256, 5) void k_A(const float* __restrict__ x, const float* __restrict__ W,
                                              const float* __restrict__ att_src, const float* __restrict__ att_dst,
                                              const float* __restrict__ W_edge, const float* __restrict__ att_edge,
                                              const int* __restrict__ ei, const float* __restrict__ ew,
                                              unsigned short* __restrict__ xph, float* __restrict__ a_src,
                                              float* __restrict__ a_dst, float* __restrict__ scal,
                                              int* __restrict__ bcur, uint2* __restrict__ staging,
                                              float* __restrict__ ewPart) {
    __shared__ float sx[32 * 128];  // 16 KB (gemm) / aliased by p1 scratch
    __shared__ float sW[32 * 128];  // 16 KB
    int t = threadIdx.x;

    if (blockIdx.x < NCH) {
        // ---------------- p1: partition edges into 256-node dst buckets ------
        int* cnt   = (int*)sx;          // NBK ints
        int* gbase = cnt + NBK;         // NBK ints
        float* wred = (float*)(gbase + NBK);
        for (int i = t; i < NBK; i += 256) cnt[i] = 0;
        __syncthreads();

        int e0 = blockIdx.x * PCH;
        int lr[16];
        float s_ew = 0.f;
        #pragma unroll
        for (int i = 0; i < 16; i++) {
            int e = e0 + i * 256 + t;
            lr[i] = 0;
            if (e < E_EDGES) {
                int d = ei[E_EDGES + e];
                s_ew += ew[e];
                lr[i] = atomicAdd(&cnt[d >> 8], 1);
            }
        }
        #pragma unroll
        for (int off = 32; off; off >>= 1) s_ew += __shfl_down(s_ew, off, 64);
        if ((t & 63) == 0) wred[t >> 6] = s_ew;
        __syncthreads();
        if (t == 0) ewPart[blockIdx.x] = wred[0] + wred[1] + wred[2] + wred[3];
        for (int i = t; i < NBK; i += 256) gbase[i] = atomicAdd(&bcur[i], cnt[i]);
        __syncthreads();

        #pragma unroll
        for (int i = 0; i < 16; i++) {
            int e = e0 + i * 256 + t;
            if (e < E_EDGES) {
                int s = ei[e];
                int d = ei[E_EDGES + e];
                float w = ew[e];
                int b = d >> 8;
                uint2 ent;
                ent.x = (unsigned int)s |
                        ((unsigned int)__half_as_ushort(__float2half_rn(w)) << 16);
                ent.y = (unsigned int)d;
                staging[(size_t)b * BCAP + gbase[b] + lr[i]] = ent;
            }
        }
        return;
    }

    // ---------------- gemm: xp = x @ W (fp16), a_src/a_dst -------------------
    int gb = blockIdx.x - NCH;
    if (gb == 0 && t < 128) {
        float p = W_edge[t] * att_edge[t];
        #pragma unroll
        for (int off = 16; off; off >>= 1) p += __shfl_down(p, off, 32);
        if ((t & 31) == 0) scal[4 + (t >> 5)] = p;
    }
    int r0 = gb * 32;
    int tc = t & 31;   // col group: cols tc*4..tc*4+3
    int tr = t >> 5;   // row group: rows tr*4..tr*4+3

    for (int i = t; i < 1024; i += 256) {
        int row = i >> 5;
        float4 v = make_float4(0.f, 0.f, 0.f, 0.f);
        if (r0 + row < N_NODES) v = ((const float4*)x)[(size_t)(r0 + row) * 32 + (i & 31)];
        ((float4*)sx)[i] = v;
    }

    float4 acc[4];
    #pragma unroll
    for (int r = 0; r < 4; r++) acc[r] = make_float4(0.f, 0.f, 0.f, 0.f);

    for (int kc = 0; kc < 128; kc += 32) {
        __syncthreads();
        for (int i = t; i < 1024; i += 256)
            ((float4*)sW)[i] = ((const float4*)W)[(size_t)kc * 32 + i];
        __syncthreads();
        #pragma unroll 4
        for (int k4 = 0; k4 < 8; k4++) {
            float4 w0 = ((float4*)sW)[(k4 * 4 + 0) * 32 + tc];
            float4 w1 = ((float4*)sW)[(k4 * 4 + 1) * 32 + tc];
            float4 w2 = ((float4*)sW)[(k4 * 4 + 2) * 32 + tc];
            float4 w3 = ((float4*)sW)[(k4 * 4 + 3) * 32 + tc];
            #pragma unroll
            for (int r = 0; r < 4; r++) {
                float4 xv = ((float4*)sx)[(tr * 4 + r) * 32 + (kc >> 2) + k4];
                acc[r] = fma4(xv.x, w0, acc[r]);
                acc[r] = fma4(xv.y, w1, acc[r]);
                acc[r] = fma4(xv.z, w2, acc[r]);
                acc[r] = fma4(xv.w, w3, acc[r]);
            }
        }
    }

    float4 s4 = ((const float4*)att_src)[tc];
    float4 d4 = ((const float4*)att_dst)[tc];
    int h = tc >> 3;
    #pragma unroll
    for (int r = 0; r < 4; r++) {
        int row = r0 + tr * 4 + r;
        if (row < N_NODES) {
            __half2 h01 = __floats2half2_rn(acc[r].x, acc[r].y);
            __half2 h23 = __floats2half2_rn(acc[r].z, acc[r].w);
            uint2 pk;
            pk.x = *(unsigned int*)&h01;
            pk.y = *(unsigned int*)&h23;
            ((uint2*)xph)[(size_t)row * 32 + tc] = pk;
            float ps = acc[r].x * s4.x + acc[r].y * s4.y + acc[r].z * s4.z + acc[r].w * s4.w;
            float pd = acc[r].x * d4.x + acc[r].y * d4.y + acc[r].z * d4.z + acc[r].w * d4.w;
            ps += __shfl_down(ps, 4, 8); ps += __shfl_down(ps, 2, 8); ps += __shfl_down(ps, 1, 8);
            pd += __shfl_down(pd, 4, 8); pd += __shfl_down(pd, 2, 8); pd += __shfl_down(pd, 1, 8);
            if ((tc & 7) == 0) {
                a_src[(size_t)row * 4 + h] = ps;
                a_dst[(size_t)row * 4 + h] = pd;
            }
        }
    }
}

// pass 2: bucket -> padded CSR + counts; block 0 also ew total.
__global__ __launch_bounds__(256) void k_p2(const uint2* __restrict__ staging,
                                            const int* __restrict__ bcur,
                                            const float* __restrict__ ewPart,
                                            unsigned int* __restrict__ pairs,
                                            int* __restrict__ counts, float* __restrict__ scal) {
    int b = blockIdx.x, t = threadIdx.x;
    __shared__ int cnt2[256];
    __shared__ float wr2[4];
    if (b == 0) {
        float s = 0.f;
        for (int i = t; i < NCH; i += 256) s += ewPart[i];
        #pragma unroll
        for (int off = 32; off; off >>= 1) s += __shfl_down(s, off, 64);
        if ((t & 63) == 0) wr2[t >> 6] = s;
    }
    cnt2[t] = 0;
    __syncthreads();
    if (b == 0 && t == 0) scal[0] = wr2[0] + wr2[1] + wr2[2] + wr2[3];
    int tot = bcur[b];
    const uint2* sg = staging + (size_t)b * BCAP;
    for (int i = t; i < tot; i += 256) {
        uint2 ent = sg[i];
        int d = (int)ent.y;
        int r = atomicAdd(&cnt2[d & 255], 1);
        pairs[(size_t)d * PAD + r] = ent.x;
    }
    __syncthreads();
    int n = (b << 8) + t;
    if (n < N_NODES) counts[n] = cnt2[t];
}

// pass 3: wave-per-node aggregate, NO barriers, fully-unrolled 16-edge gather.
// Out-of-range lanes carry alpha=0, s=n (padded gathers hit the hot self row).
__global__ __launch_bounds__(256) void k_p3(const unsigned int* __restrict__ xpu,
                                            const float* __restrict__ a_src,
                                            const float* __restrict__ a_dst,
                                            const int* __restrict__ counts,
                                            const unsigned int* __restrict__ pairs,
                                            const float* __restrict__ scal,
                                            const float* __restrict__ bias,
                                            const float* __restrict__ gamma,
                                            const float* __restrict__ beta,
                                            float* __restrict__ out) {
    int lane = threadIdx.x & 63;
    int wid = blockIdx.x * 4 + (threadIdx.x >> 6);
    int h = lane >> 4;        // head for this lane's channel pair
    int em = lane & 15;       // edge slot within a 16-edge batch
    int shb = lane & 48;      // shuffle base: this head's alpha group
    float4 K = *(const float4*)(scal + 4);
    float Kh = sel4(K, h);
    float mean_ew = scal[0] * (1.0f / E_EDGES);

    int n = wid;
    if (n >= N_NODES) return;
    {
        int cnt = counts[n];
        float4 ad4 = *(const float4*)(a_dst + (size_t)4 * n);
        float4 as4 = *(const float4*)(a_src + (size_t)4 * n);
        float adh = sel4(ad4, h);
        float aself = exp2f(lrelu(sel4(as4, h) + adh + Kh * mean_ew) * LOG2E);

        unsigned int pv = xpu[(size_t)n * 64 + lane];   // channels 2l, 2l+1
        float2 f = __half22float2(*(__half2*)&pv);
        float acc0 = aself * f.x, acc1 = aself * f.y;
        float den = 0.f;

        for (int base = 0; base < cnt; base += 16) {
            int e = base + em;
            float alpha = 0.f;
            int s = n;
            if (e < cnt) {
                unsigned int pk = pairs[(size_t)n * PAD + e];
                s = (int)(pk & 0xFFFFu);
                float w = __half2float(__ushort_as_half((unsigned short)(pk >> 16)));
                float4 av = *(const float4*)(a_src + (size_t)4 * s);
                alpha = exp2f(lrelu(sel4(av, h) + adh + Kh * w) * LOG2E);
            }
            den += alpha;
            #pragma unroll
            for (int j = 0; j < 16; j++) {
                int sj   = __shfl(s, shb + j, 64);
                float aj = __shfl(alpha, shb + j, 64);
                unsigned int p2 = xpu[(size_t)sj * 64 + lane];
                float2 g = __half22float2(*(__half2*)&p2);
                acc0 = fmaf(aj, g.x, acc0);
                acc1 = fmaf(aj, g.y, acc1);
            }
        }
        // reduce den across the 16 lanes sharing this head
        den += __shfl_xor(den, 1, 64);
        den += __shfl_xor(den, 2, 64);
        den += __shfl_xor(den, 4, 64);
        den += __shfl_xor(den, 8, 64);
        den += aself;

        float inv = 1.0f / (den + 1e-16f);
        float2 b2 = ((const float2*)bias)[lane];
        float y0 = fmaf(acc0, inv, b2.x);
        float y1 = fmaf(acc1, inv, b2.y);

        // LayerNorm over 128 channels (2 per lane) via full-wave xor reduce
        float s1 = y0 + y1;
        #pragma unroll
        for (int off = 1; off < 64; off <<= 1) s1 += __shfl_xor(s1, off, 64);
        float mu = s1 * (1.f / 128.f);
        float d0 = y0 - mu, d1 = y1 - mu;
        float s2 = d0 * d0 + d1 * d1;
        #pragma unroll
        for (int off = 1; off < 64; off <<= 1) s2 += __shfl_xor(s2, off, 64);
        float rstd = rsqrtf(s2 * (1.f / 128.f) + LN_EPS);
        float2 g2 = ((const float2*)gamma)[lane];
        float2 be2 = ((const float2*)beta)[lane];
        float o0 = fmaf(d0 * rstd, g2.x, be2.x);
        float o1 = fmaf(d1 * rstd, g2.y, be2.y);
        o0 = o0 > 0.f ? o0 : expm1f(o0);
        o1 = o1 > 0.f ? o1 : expm1f(o1);
        float2 o; o.x = o0; o.y = o1;
        ((float2*)out)[(size_t)n * 64 + lane] = o;
    }
}

extern "C" void kernel_launch(void* const* d_in, const int* in_sizes, int n_in,
                              void* d_out, int out_size, void* d_ws, size_t ws_size,
                              hipStream_t stream) {
    const float* x        = (const float*)d_in[0];
    const int*   ei       = (const int*)d_in[1];
    const float* ew       = (const float*)d_in[2];
    const float* W        = (const float*)d_in[3];
    const float* att_src  = (const float*)d_in[4];
    const float* att_dst  = (const float*)d_in[5];
    const float* W_edge   = (const float*)d_in[6];
    const float* att_edge = (const float*)d_in[7];
    const float* bias     = (const float*)d_in[8];
    const float* gamma    = (const float*)d_in[9];
    const float* beta     = (const float*)d_in[10];
    float* out = (float*)d_out;

    char* ws = (char*)d_ws;
    float* scal      = (float*)(ws + OFF_SCAL);
    int*   bcur      = (int*)(ws + OFF_BCUR);
    float* ewPart    = (float*)(ws + OFF_EWPART);
    int*   counts    = (int*)(ws + OFF_COUNTS);
    float* a_src     = (float*)(ws + OFF_ASRC);
    float* a_dst     = (float*)(ws + OFF_ADST);
    unsigned short* xph = (unsigned short*)(ws + OFF_XPH);
    unsigned int* pairs = (unsigned int*)(ws + OFF_PAIRS);
    uint2* staging   = (uint2*)(ws + OFF_STAGE);

    hipMemsetAsync(bcur, 0, NBK * sizeof(int), stream);
    k_A<<<NCH + NGB, TPB, 0, stream>>>(x, W, att_src, att_dst, W_edge, att_edge, ei, ew,
                                       xph, a_src, a_dst, scal, bcur, staging, ewPart);
    k_p2<<<NBK, TPB, 0, stream>>>(staging, bcur, ewPart, pairs, counts, scal);
    k_p3<<<12500, TPB, 0, stream>>>((const unsigned int*)xph, a_src, a_dst, counts, pairs, scal,
                                    bias, gamma, beta, out);
}